// Round 10
// baseline (95.234 us; speedup 1.0000x reference)
//
#include <hip/hip_runtime.h>

typedef short bf16x8 __attribute__((ext_vector_type(8)));
typedef float f32x4 __attribute__((ext_vector_type(4)));
typedef unsigned uint4v __attribute__((ext_vector_type(4)));

#define B_    8
#define L_    500
#define LP    512
#define H_    16
#define DK    64
#define DM    1024
#define MP    4096
#define NT    8      // attn: 512 / 64 keys per tile

static __device__ __forceinline__ unsigned short f2bf(float x) {
  unsigned u = __float_as_uint(x);
  u += 0x7fffu + ((u >> 16) & 1u);   // RNE
  return (unsigned short)(u >> 16);
}

static __device__ __forceinline__ unsigned cvtpk(float lo, float hi) {
  unsigned r;
  asm("v_cvt_pk_bf16_f32 %0, %1, %2" : "=v"(r) : "v"(lo), "v"(hi));
  return r;
}

static __device__ __forceinline__ void gload16(const void* g, void* l) {
  __builtin_amdgcn_global_load_lds(
      (const __attribute__((address_space(1))) void*)g,
      (__attribute__((address_space(3))) void*)l, 16, 0, 0);
}

static __device__ __forceinline__ f32x4 MF(bf16x8 a, bf16x8 b, f32x4 c) {
  return __builtin_amdgcn_mfma_f32_16x16x32_bf16(a, b, c, 0, 0, 0);
}

// ---------- merged prep: conv_x (bx<2048) + conv_w transpose (bx>=2048) ----------
__global__ __launch_bounds__(256) void conv_kernel(
    const float* __restrict__ iq, const float* __restrict__ ik,
    const float* __restrict__ iv,
    const float* __restrict__ wq, const float* __restrict__ wk,
    const float* __restrict__ wv,
    unsigned short* __restrict__ X, unsigned short* __restrict__ Wt) {
  const int z = blockIdx.y;
  const int bx = blockIdx.x;
  const int tid = threadIdx.x;
  if (bx < 2048) {
    const float* src = (z == 0) ? iq : (z == 1) ? ik : iv;
    const size_t off = ((size_t)bx * 256 + tid) * 8;
    const int m = (int)(off >> 10);
    unsigned short o[8];
    if (m < 4000) {
      const float4 a = *(const float4*)(src + off);
      const float4 b = *(const float4*)(src + off + 4);
      o[0]=f2bf(a.x); o[1]=f2bf(a.y); o[2]=f2bf(a.z); o[3]=f2bf(a.w);
      o[4]=f2bf(b.x); o[5]=f2bf(b.y); o[6]=f2bf(b.z); o[7]=f2bf(b.w);
    } else {
#pragma unroll
      for (int i = 0; i < 8; ++i) o[i] = 0;
    }
    uint4 pk;
    pk.x = (unsigned)o[0] | ((unsigned)o[1] << 16);
    pk.y = (unsigned)o[2] | ((unsigned)o[3] << 16);
    pk.z = (unsigned)o[4] | ((unsigned)o[5] << 16);
    pk.w = (unsigned)o[6] | ((unsigned)o[7] << 16);
    *(uint4*)(X + (size_t)z * MP * DM + off) = pk;
    return;
  }
  const int bw = bx - 2048;
  const float* W = (z == 0) ? wq : (z == 1) ? wk : wv;
  const int k0 = (bw >> 4) * 64;
  const int n0 = (bw & 15) * 64;
  __shared__ float t[64][65];
  const int row = tid >> 2;
  const int cb  = (tid & 3) * 16;
#pragma unroll
  for (int s = 0; s < 4; ++s) {
    const float4 v = *(const float4*)(W + (size_t)(k0 + row) * DM + n0 + cb + s * 4);
    t[row][cb + s * 4 + 0] = v.x; t[row][cb + s * 4 + 1] = v.y;
    t[row][cb + s * 4 + 2] = v.z; t[row][cb + s * 4 + 3] = v.w;
  }
  __syncthreads();
  const int nr = tid >> 2;
  const int kb = (tid & 3) * 16;
#pragma unroll
  for (int s = 0; s < 2; ++s) {
    unsigned short o[8];
#pragma unroll
    for (int e = 0; e < 8; ++e) o[e] = f2bf(t[kb + s * 8 + e][nr]);
    uint4 pk;
    pk.x = (unsigned)o[0] | ((unsigned)o[1] << 16);
    pk.y = (unsigned)o[2] | ((unsigned)o[3] << 16);
    pk.z = (unsigned)o[4] | ((unsigned)o[5] << 16);
    pk.w = (unsigned)o[6] | ((unsigned)o[7] << 16);
    *(uint4*)(Wt + (size_t)z * DM * DM + (size_t)(n0 + nr) * DM + k0 + kb + s * 8) = pk;
  }
}

// ---------- fused QKV projection GEMM (m97 + 3-ring, compile-time buffer unroll) ----------
#define GSTEP(T_, BUF_, NBUF_)                                                    \
  {                                                                               \
    if ((T_) < 30) {                                                              \
      const int kn_ = ((T_) + 2) * 32;                                            \
      gload16(gA0 + kn_, &sA[NBUF_][c0 * 8]);                                     \
      gload16(gA1 + kn_, &sA[NBUF_][c1 * 8]);                                     \
      gload16(gB0 + kn_, &sB[NBUF_][c0 * 8]);                                     \
      gload16(gB1 + kn_, &sB[NBUF_][c1 * 8]);                                     \
    }                                                                             \
    bf16x8 af[4], bfr[4];                                                         \
    _Pragma("unroll") for (int s = 0; s < 4; ++s) {                               \
      af[s]  = *(const bf16x8*)&sA[BUF_][(wr * 64 + s * 16 + lr) * 32 + lg * 8];  \
      bfr[s] = *(const bf16x8*)&sB[BUF_][(wc * 64 + s * 16 + lr) * 32 + lg * 8];  \
    }                                                                             \
    _Pragma("unroll") for (int i = 0; i < 4; ++i)                                 \
      _Pragma("unroll") for (int j = 0; j < 4; ++j)                               \
        acc[i][j] = MF(af[i], bfr[j], acc[i][j]);                                 \
    if ((T_) < 31) {                                                              \
      if ((T_) < 30) asm volatile("s_waitcnt vmcnt(4)" ::: "memory");             \
      else           asm volatile("s_waitcnt vmcnt(0)" ::: "memory");             \
      __builtin_amdgcn_s_barrier();                                               \
      __builtin_amdgcn_sched_barrier(0);                                          \
    }                                                                             \
  }

__global__ __launch_bounds__(256) void gemm_qkv_kernel(
    const unsigned short* __restrict__ X, const unsigned short* __restrict__ Wt,
    const float* __restrict__ bq, const float* __restrict__ bk,
    const float* __restrict__ bv,
    unsigned short* __restrict__ qo, unsigned short* __restrict__ ko,
    unsigned short* __restrict__ vo) {
  const int z = blockIdx.y;
  const unsigned short* A  = X  + (size_t)z * MP * DM;
  const unsigned short* Bw = Wt + (size_t)z * DM * DM;
  const float* bias = (z == 0) ? bq : (z == 1) ? bk : bv;
  unsigned short* out = (z == 0) ? qo : (z == 1) ? ko : vo;

  const int bid = blockIdx.x;
  const int xg = bid & 7, y = bid >> 3;
  const int tm = xg + 8 * (y >> 3);           // 0..31
  const int tn = y & 7;                       // 0..7
  const int tid = threadIdx.x;
  const int lane = tid & 63, wid = tid >> 6;
  const int wr = wid >> 1, wc = wid & 1;
  const int lg = lane >> 4, lr = lane & 15;

  __shared__ __attribute__((aligned(16))) unsigned short sA[3][128 * 32];
  __shared__ __attribute__((aligned(16))) unsigned short sB[3][128 * 32];

  const int c0 = tid, c1 = tid + 256;
  const int ar0 = c0 >> 2, ak0 = (c0 & 3) * 8;
  const int ar1 = c1 >> 2, ak1 = (c1 & 3) * 8;
  const unsigned short* Ab = A  + (size_t)tm * 128 * DM;
  const unsigned short* Bb = Bw + (size_t)tn * 128 * DM;
  const unsigned short* gA0 = Ab + (size_t)ar0 * DM + ak0;
  const unsigned short* gA1 = Ab + (size_t)ar1 * DM + ak1;
  const unsigned short* gB0 = Bb + (size_t)ar0 * DM + ak0;
  const unsigned short* gB1 = Bb + (size_t)ar1 * DM + ak1;

  f32x4 acc[4][4];
#pragma unroll
  for (int i = 0; i < 4; ++i)
#pragma unroll
    for (int j = 0; j < 4; ++j) acc[i][j] = (f32x4){0.f, 0.f, 0.f, 0.f};

  // prologue: tiles 0 (buf0), 1 (buf1) in flight; wait tile0 only
  gload16(gA0, &sA[0][c0 * 8]);
  gload16(gA1, &sA[0][c1 * 8]);
  gload16(gB0, &sB[0][c0 * 8]);
  gload16(gB1, &sB[0][c1 * 8]);
  gload16(gA0 + 32, &sA[1][c0 * 8]);
  gload16(gA1 + 32, &sA[1][c1 * 8]);
  gload16(gB0 + 32, &sB[1][c0 * 8]);
  gload16(gB1 + 32, &sB[1][c1 * 8]);
  asm volatile("s_waitcnt vmcnt(4)" ::: "memory");
  __builtin_amdgcn_s_barrier();
  __builtin_amdgcn_sched_barrier(0);

  for (int t = 0; t < 30; t += 3) {
    GSTEP(t,     0, 2);
    GSTEP(t + 1, 1, 0);
    GSTEP(t + 2, 2, 1);
  }
  GSTEP(30, 0, 2);
  GSTEP(31, 1, 0);

  // epilogue: bias + scatter to [b][h][l(512)][64] bf16
  const int nbase = tn * 128 + wc * 64 + lr;
  float bias4[4];
#pragma unroll
  for (int ns = 0; ns < 4; ++ns) bias4[ns] = bias[nbase + ns * 16];

#pragma unroll
  for (int ms = 0; ms < 4; ++ms) {
#pragma unroll
    for (int r = 0; r < 4; ++r) {
      const int m = tm * 128 + wr * 64 + ms * 16 + lg * 4 + r;
      if (m < 4000) {
        const unsigned batch = (unsigned)m / 500u;
        const int lrow = m - (int)batch * 500;
#pragma unroll
        for (int ns = 0; ns < 4; ++ns) {
          const int n = nbase + ns * 16;
          const int hh = n >> 6, d = n & 63;
          out[(((size_t)batch * H_ + hh) * LP + lrow) * DK + d] =
              f2bf(acc[ms][ns][r] + bias4[ns]);
        }
      }
    }
  }
}

// ---------- V [bh][l][d] -> Vt [bh][d][l], zero-fill l >= 500 ----------
__global__ __launch_bounds__(256) void transpose_v_kernel(
    const unsigned short* __restrict__ v, unsigned short* __restrict__ vt) {
  const int bh = blockIdx.y;
  const int l0 = blockIdx.x * 64;
  __shared__ unsigned short t[64][72];
  const int tid = threadIdx.x;
  const int lrw = tid >> 2, dc = (tid & 3) * 16;
  const int gl = l0 + lrw;
  if (gl < L_) {
    *(uint4*)&t[lrw][dc]     = *(const uint4*)(v + ((size_t)bh * LP + gl) * DK + dc);
    *(uint4*)&t[lrw][dc + 8] = *(const uint4*)(v + ((size_t)bh * LP + gl) * DK + dc + 8);
  } else {
    const uint4 zz = {0u, 0u, 0u, 0u};
    *(uint4*)&t[lrw][dc]     = zz;
    *(uint4*)&t[lrw][dc + 8] = zz;
  }
  __syncthreads();
  const int dr = tid >> 2, lcb = (tid & 3) * 16;
#pragma unroll
  for (int s = 0; s < 2; ++s) {
    unsigned short e[8];
#pragma unroll
    for (int i = 0; i < 8; ++i) e[i] = t[lcb + s * 8 + i][dr];
    uint4 o;
    o.x = (unsigned)e[0] | ((unsigned)e[1] << 16);
    o.y = (unsigned)e[2] | ((unsigned)e[3] << 16);
    o.z = (unsigned)e[4] | ((unsigned)e[5] << 16);
    o.w = (unsigned)e[6] | ((unsigned)e[7] << 16);
    *(uint4*)(vt + ((size_t)bh * DK + dr) * LP + l0 + lcb + s * 8) = o;
  }
}

// ---------- flash attention: QBLK=128, 8 waves, staged K/V, sigma-permuted QK^T,
//            P entirely in registers ----------
__global__ __launch_bounds__(512, 2) void attn_kernel(
    const unsigned short* __restrict__ q, const unsigned short* __restrict__ k,
    const unsigned short* __restrict__ vt, const float* __restrict__ rel,
    float* __restrict__ out) {
  const int id = blockIdx.x;           // XCD = id%8 = bh%8 -> per-XCD K/V L2 residency
  const int bh = id & 127, qc = id >> 7;   // qc 0..3, 128 q-rows each
  const int b = bh >> 4, h = bh & 15;
  const int tid = threadIdx.x;
  const int lane = tid & 63, wid = tid >> 6;    // 8 waves
  const int lg = lane >> 4, lr = lane & 15;

  __shared__ unsigned short kt[2][2][64][32];   // [buf][dhalf][key][d&31]
  __shared__ unsigned short vtt[2][2][64][32];  // [buf][keyhalf][d][key&31]
  __shared__ float relb[640];

  const float LOG2E = 1.44269504f;
  const float SC = 0.125f * LOG2E;
  const int rbase = qc * 128 - 12;
  for (int i = tid; i < 639; i += 512) {
    int idx = rbase + i;
    idx = idx < 0 ? 0 : (idx > 998 ? 998 : idx);
    relb[i] = rel[h * 999 + idx] * LOG2E;
  }

  const int qrow = qc * 128 + wid * 16 + lr;
  const unsigned short* qp = q + ((size_t)bh * LP + qrow) * DK + lg * 8;
  const bf16x8 qf0 = *(const bf16x8*)qp;
  const bf16x8 qf1 = *(const bf16x8*)(qp + 32);

  // staging: 512 threads, one uint4 each for K and V per tile
  const int kj = tid >> 3, dcs = (tid & 7) * 8;
  const unsigned short* kgp = k + ((size_t)bh * LP + kj) * DK + dcs;
  unsigned short* kls = &kt[0][dcs >> 5][kj][dcs & 31];
  const int vd = tid >> 3, vkg = (tid & 7) * 8;
  const unsigned short* vgp = vt + ((size_t)bh * DK + vd) * LP + vkg;
  unsigned short* vls = &vtt[0][vkg >> 5][vd][vkg & 31];

  const int sig0 = 8 * (lr >> 2) + (lr & 3);   // sigma base
  const int qin = wid * 16 + lr;               // 0..127

  f32x4 o[4];
#pragma unroll
  for (int d = 0; d < 4; ++d) o[d] = (f32x4){0.f, 0.f, 0.f, 0.f};
  float mrun = -1e30f, lrun = 0.f;

  uint4 ka0 = *(const uint4*)(kgp);
  uint4 va0 = *(const uint4*)(vgp);

  for (int t = 0; t < NT; ++t) {
    const int buf = t & 1;
    *(uint4*)(kls + buf * 4096) = ka0;
    *(uint4*)(vls + buf * 4096) = va0;
    __syncthreads();

    if (t < NT - 1) {
      ka0 = *(const uint4*)(kgp + (size_t)(t + 1) * 64 * DK);
      va0 = *(const uint4*)(vgp + (t + 1) * 64);
    }

    f32x4 s[2][2];
#pragma unroll
    for (int kc = 0; kc < 2; ++kc)
#pragma unroll
      for (int hf = 0; hf < 2; ++hf) {
        const int sg = kc * 32 + hf * 4 + sig0;
        const bf16x8 a0 = *(const bf16x8*)&kt[buf][0][sg][lg * 8];
        const bf16x8 a1 = *(const bf16x8*)&kt[buf][1][sg][lg * 8];
        f32x4 ss = (f32x4){0.f, 0.f, 0.f, 0.f};
        ss = __builtin_amdgcn_mfma_f32_16x16x32_bf16(a0, qf0, ss, 0, 0, 0);
        ss = __builtin_amdgcn_mfma_f32_16x16x32_bf16(a1, qf1, ss, 0, 0, 0);
        s[kc][hf] = ss;
      }

    float sc[2][2][4];
#pragma unroll
    for (int kc = 0; kc < 2; ++kc)
#pragma unroll
      for (int hf = 0; hf < 2; ++hf) {
        const int bidx = qin - (t * 64 + kc * 32 + 8 * lg + 4 * hf) + 511;
#pragma unroll
        for (int r = 0; r < 4; ++r)
          sc[kc][hf][r] = s[kc][hf][r] * SC + relb[bidx - r];
      }
    if (t == NT - 1) {
#pragma unroll
      for (int hf = 0; hf < 2; ++hf)
#pragma unroll
        for (int r = 0; r < 4; ++r)
          if (8 * lg + 4 * hf + r >= 20) sc[1][hf][r] = -1e30f;
    }

    float m0 = fmaxf(fmaxf(sc[0][0][0], sc[0][0][1]), fmaxf(sc[0][0][2], sc[0][0][3]));
    float m1 = fmaxf(fmaxf(sc[0][1][0], sc[0][1][1]), fmaxf(sc[0][1][2], sc[0][1][3]));
    float m2 = fmaxf(fmaxf(sc[1][0][0], sc[1][0][1]), fmaxf(sc[1][0][2], sc[1][0][3]));
    float m3 = fmaxf(fmaxf(sc[1][1][0], sc[1][1][1]), fmaxf(sc[1][1][2], sc[1][1][3]));
    const float mloc = fmaxf(fmaxf(m0, m1), fmaxf(m2, m3));
    if (!__all(mloc - mrun <= 11.5f)) {
      float mx = fmaxf(mloc, mrun);
      mx = fmaxf(mx, __shfl_xor(mx, 16));
      mx = fmaxf(mx, __shfl_xor(mx, 32));
      const float alpha = exp2f(mrun - mx);
      mrun = mx;
      lrun *= alpha;
#pragma unroll
      for (int d = 0; d < 4; ++d) {
        o[d][0] *= alpha; o[d][1] *= alpha; o[d][2] *= alpha; o[d][3] *= alpha;
      }
    }

    float rs = 0.f;
    unsigned pw[2][4];
#pragma unroll
    for (int kc = 0; kc < 2; ++kc)
#pragma unroll
      for (int hf = 0; hf < 2; ++hf) {
        float p0 = exp2f(sc[kc][hf][0] - mrun);
        float p1 = exp2f(sc[kc][hf][1] - mrun);
        float p2 = exp2f(sc[kc][hf][2] - mrun);
        float p3 = exp2f(sc[kc][hf][3] - mrun);
        rs += (p0 + p1) + (p2 + p3);
        pw[kc][hf * 2 + 0] = cvtpk(p0, p1);
        pw[kc][hf * 2 + 1] = cvtpk(p2, p3);
      }
    rs += __shfl_xor(rs, 16);
    rs += __shfl_xor(rs, 32);
    lrun += rs;

#pragma unroll
    for (int kc = 0; kc < 2; ++kc) {
      union { uint4v u; bf16x8 v; } cv;
      cv.u = (uint4v){pw[kc][0], pw[kc][1], pw[kc][2], pw[kc][3]};
      const bf16x8 pf = cv.v;
#pragma unroll
      for (int db = 0; db < 4; ++db) {
        const bf16x8 vf = *(const bf16x8*)&vtt[buf][kc][db * 16 + lr][lg * 8];
        o[db] = __builtin_amdgcn_mfma_f32_16x16x32_bf16(vf, pf, o[db], 0, 0, 0);
      }
    }
  }

  if (qrow < L_) {
    const float inv = 1.0f / lrun;
    float* op = out + ((size_t)b * L_ + qrow) * DM + h * DK + lg * 4;
#pragma unroll
    for (int db = 0; db < 4; ++db) {
      float4 v;
      v.x = o[db][0] * inv; v.y = o[db][1] * inv;
      v.z = o[db][2] * inv; v.w = o[db][3] * inv;
      *(float4*)(op + db * 16) = v;
    }
  }
}

extern "C" void kernel_launch(void* const* d_in, const int* in_sizes, int n_in,
                              void* d_out, int out_size, void* d_ws, size_t ws_size,
                              hipStream_t stream) {
  const float* iq  = (const float*)d_in[0];
  const float* ik  = (const float*)d_in[1];
  const float* iv  = (const float*)d_in[2];
  const float* wq  = (const float*)d_in[3];
  const float* bq  = (const float*)d_in[4];
  const float* wk  = (const float*)d_in[5];
  const float* bk  = (const float*)d_in[6];
  const float* wv  = (const float*)d_in[7];
  const float* bv  = (const float*)d_in[8];
  const float* rel = (const float*)d_in[9];
  float* out = (float*)d_out;

  char* w = (char*)d_ws;
  unsigned short* X   = (unsigned short*)(w);                 // [3][4096][1024] bf16
  unsigned short* Wt  = (unsigned short*)(w + 25165824);      // [3][1024][1024] bf16 (n,k)
  unsigned short* qb  = (unsigned short*)(w + 31457280);      // [128][512][64] bf16
  unsigned short* kb  = (unsigned short*)(w + 39845888);
  unsigned short* vb  = (unsigned short*)(w + 48234496);
  unsigned short* vtb = (unsigned short*)(w + 56623104);      // [128][64][512] bf16

  conv_kernel<<<dim3(2304, 3), 256, 0, stream>>>(iq, ik, iv, wq, wk, wv, X, Wt);
  gemm_qkv_kernel<<<dim3(256, 3), 256, 0, stream>>>(X, Wt, bq, bk, bv, qb, kb, vb);
  transpose_v_kernel<<<dim3(8, 128), 256, 0, stream>>>(vb, vtb);
  attn_kernel<<<512, 512, 0, stream>>>(qb, kb, vtb, rel, out);
}

// Round 11
// 84.295 us; speedup vs baseline: 1.1298x; 1.1298x over previous
//
#include <hip/hip_runtime.h>

typedef short bf16x8 __attribute__((ext_vector_type(8)));
typedef float f32x4 __attribute__((ext_vector_type(4)));
typedef unsigned uint4v __attribute__((ext_vector_type(4)));

#define B_    8
#define L_    500
#define LP    512
#define H_    16
#define DK    64
#define DM    1024
#define MP    4096
#define NT    8      // attn: 512 / 64 keys per tile

static __device__ __forceinline__ unsigned short f2bf(float x) {
  unsigned u = __float_as_uint(x);
  u += 0x7fffu + ((u >> 16) & 1u);   // RNE
  return (unsigned short)(u >> 16);
}

static __device__ __forceinline__ unsigned cvtpk(float lo, float hi) {
  unsigned r;
  asm("v_cvt_pk_bf16_f32 %0, %1, %2" : "=v"(r) : "v"(lo), "v"(hi));
  return r;
}

static __device__ __forceinline__ void gload16(const void* g, void* l) {
  __builtin_amdgcn_global_load_lds(
      (const __attribute__((address_space(1))) void*)g,
      (__attribute__((address_space(3))) void*)l, 16, 0, 0);
}

static __device__ __forceinline__ f32x4 MF(bf16x8 a, bf16x8 b, f32x4 c) {
  return __builtin_amdgcn_mfma_f32_16x16x32_bf16(a, b, c, 0, 0, 0);
}

// ---------- merged prep: conv_x (bx<2048) + conv_w (2048<=bx<2304) + vt tail zero ----------
__global__ __launch_bounds__(256) void conv_kernel(
    const float* __restrict__ iq, const float* __restrict__ ik,
    const float* __restrict__ iv,
    const float* __restrict__ wq, const float* __restrict__ wk,
    const float* __restrict__ wv,
    unsigned short* __restrict__ X, unsigned short* __restrict__ Wt,
    unsigned short* __restrict__ vt) {
  const int z = blockIdx.y;
  const int bx = blockIdx.x;
  const int tid = threadIdx.x;
  if (bx < 2048) {
    const float* src = (z == 0) ? iq : (z == 1) ? ik : iv;
    const size_t off = ((size_t)bx * 256 + tid) * 8;
    const int m = (int)(off >> 10);
    unsigned short o[8];
    if (m < 4000) {
      const float4 a = *(const float4*)(src + off);
      const float4 b = *(const float4*)(src + off + 4);
      o[0]=f2bf(a.x); o[1]=f2bf(a.y); o[2]=f2bf(a.z); o[3]=f2bf(a.w);
      o[4]=f2bf(b.x); o[5]=f2bf(b.y); o[6]=f2bf(b.z); o[7]=f2bf(b.w);
    } else {
#pragma unroll
      for (int i = 0; i < 8; ++i) o[i] = 0;
    }
    uint4 pk;
    pk.x = (unsigned)o[0] | ((unsigned)o[1] << 16);
    pk.y = (unsigned)o[2] | ((unsigned)o[3] << 16);
    pk.z = (unsigned)o[4] | ((unsigned)o[5] << 16);
    pk.w = (unsigned)o[6] | ((unsigned)o[7] << 16);
    *(uint4*)(X + (size_t)z * MP * DM + off) = pk;
    return;
  }
  if (bx >= 2304) {
    // zero V^T rows l in [496,512) for all (bh, d); gemm later overwrites 496..499
    if (z == 0) {
      const int idx = (bx - 2304) * 256 + tid;      // 0..8191 = bh*64 + d
      unsigned short* p = vt + (size_t)idx * LP + 496;
      const uint4 zz = {0u, 0u, 0u, 0u};
      *(uint4*)(p)     = zz;
      *(uint4*)(p + 8) = zz;
    }
    return;
  }
  const int bw = bx - 2048;
  const float* W = (z == 0) ? wq : (z == 1) ? wk : wv;
  const int k0 = (bw >> 4) * 64;
  const int n0 = (bw & 15) * 64;
  __shared__ float t[64][65];
  const int row = tid >> 2;
  const int cb  = (tid & 3) * 16;
#pragma unroll
  for (int s = 0; s < 4; ++s) {
    const float4 v = *(const float4*)(W + (size_t)(k0 + row) * DM + n0 + cb + s * 4);
    t[row][cb + s * 4 + 0] = v.x; t[row][cb + s * 4 + 1] = v.y;
    t[row][cb + s * 4 + 2] = v.z; t[row][cb + s * 4 + 3] = v.w;
  }
  __syncthreads();
  const int nr = tid >> 2;
  const int kb = (tid & 3) * 16;
#pragma unroll
  for (int s = 0; s < 2; ++s) {
    unsigned short o[8];
#pragma unroll
    for (int e = 0; e < 8; ++e) o[e] = f2bf(t[kb + s * 8 + e][nr]);
    uint4 pk;
    pk.x = (unsigned)o[0] | ((unsigned)o[1] << 16);
    pk.y = (unsigned)o[2] | ((unsigned)o[3] << 16);
    pk.z = (unsigned)o[4] | ((unsigned)o[5] << 16);
    pk.w = (unsigned)o[6] | ((unsigned)o[7] << 16);
    *(uint4*)(Wt + (size_t)z * DM * DM + (size_t)(n0 + nr) * DM + k0 + kb + s * 8) = pk;
  }
}

// ---------- fused QKV projection GEMM (m97 structure + 3-buffer counted-vmcnt ring) ----------
// z==0/1 write q/k in [b][h][l(512)][64]; z==2 writes V^T directly: [b*16+h][d][l(512)]
__global__ __launch_bounds__(256) void gemm_qkv_kernel(
    const unsigned short* __restrict__ X, const unsigned short* __restrict__ Wt,
    const float* __restrict__ bq, const float* __restrict__ bk,
    const float* __restrict__ bv,
    unsigned short* __restrict__ qo, unsigned short* __restrict__ ko,
    unsigned short* __restrict__ vo) {
  const int z = blockIdx.y;
  const unsigned short* A  = X  + (size_t)z * MP * DM;
  const unsigned short* Bw = Wt + (size_t)z * DM * DM;
  const float* bias = (z == 0) ? bq : (z == 1) ? bk : bv;
  unsigned short* out = (z == 0) ? qo : (z == 1) ? ko : vo;

  const int bid = blockIdx.x;
  const int xg = bid & 7, y = bid >> 3;
  const int tm = xg + 8 * (y >> 3);           // 0..31
  const int tn = y & 7;                       // 0..7
  const int tid = threadIdx.x;
  const int lane = tid & 63, wid = tid >> 6;
  const int wr = wid >> 1, wc = wid & 1;
  const int lg = lane >> 4, lr = lane & 15;

  __shared__ __attribute__((aligned(16))) unsigned short sA[3][128 * 32];
  __shared__ __attribute__((aligned(16))) unsigned short sB[3][128 * 32];

  const int c0 = tid, c1 = tid + 256;
  const int ar0 = c0 >> 2, ak0 = (c0 & 3) * 8;
  const int ar1 = c1 >> 2, ak1 = (c1 & 3) * 8;
  const unsigned short* Ab = A  + (size_t)tm * 128 * DM;
  const unsigned short* Bb = Bw + (size_t)tn * 128 * DM;

  auto STAGE = [&](int t) {
    const int buf = t % 3;
    const int kn = t * 32;
    gload16(Ab + (size_t)ar0 * DM + kn + ak0, &sA[buf][c0 * 8]);
    gload16(Ab + (size_t)ar1 * DM + kn + ak1, &sA[buf][c1 * 8]);
    gload16(Bb + (size_t)ar0 * DM + kn + ak0, &sB[buf][c0 * 8]);
    gload16(Bb + (size_t)ar1 * DM + kn + ak1, &sB[buf][c1 * 8]);
  };

  f32x4 acc[4][4];
#pragma unroll
  for (int i = 0; i < 4; ++i)
#pragma unroll
    for (int j = 0; j < 4; ++j) acc[i][j] = (f32x4){0.f, 0.f, 0.f, 0.f};

  // prologue: tiles 0,1 in flight; wait tile0 (leave tile1's 4 loads in flight)
  STAGE(0); STAGE(1);
  asm volatile("s_waitcnt vmcnt(4)" ::: "memory");
  __builtin_amdgcn_s_barrier();
  __builtin_amdgcn_sched_barrier(0);

  for (int t = 0; t < 32; ++t) {
    if (t < 30) STAGE(t + 2);               // issue into buf (t+2)%3 (last read at t-1)
    const int cb = t % 3;
    bf16x8 af[4], bfr[4];
#pragma unroll
    for (int s = 0; s < 4; ++s) {
      af[s]  = *(const bf16x8*)&sA[cb][(wr * 64 + s * 16 + lr) * 32 + lg * 8];
      bfr[s] = *(const bf16x8*)&sB[cb][(wc * 64 + s * 16 + lr) * 32 + lg * 8];
    }
#pragma unroll
    for (int i = 0; i < 4; ++i)
#pragma unroll
      for (int j = 0; j < 4; ++j)
        acc[i][j] = MF(af[i], bfr[j], acc[i][j]);
    if (t < 31) {
      if (t < 30) asm volatile("s_waitcnt vmcnt(4)" ::: "memory");  // t+1 landed, t+2 in flight
      else        asm volatile("s_waitcnt vmcnt(0)" ::: "memory");  // tail: t=30 waits tile31
      __builtin_amdgcn_s_barrier();
      __builtin_amdgcn_sched_barrier(0);
    }
  }

  const int nbase = tn * 128 + wc * 64 + lr;
  float bias4[4];
#pragma unroll
  for (int ns = 0; ns < 4; ++ns) bias4[ns] = bias[nbase + ns * 16];

  if (z == 2) {
    // V^T epilogue: lane's 4 acc rows = 4 consecutive l -> one uint2 store each
#pragma unroll
    for (int ms = 0; ms < 4; ++ms) {
      const int m0 = tm * 128 + wr * 64 + ms * 16 + lg * 4;
      if (m0 < 4000) {
        const unsigned batch = (unsigned)m0 / 500u;
        const int lrow0 = m0 - (int)batch * 500;   // multiple of 4, block never straddles 500
#pragma unroll
        for (int ns = 0; ns < 4; ++ns) {
          const int n = nbase + ns * 16;
          const int hh = n >> 6, d = n & 63;
          uint2 pk;
          pk.x = (unsigned)f2bf(acc[ms][ns][0] + bias4[ns]) |
                 ((unsigned)f2bf(acc[ms][ns][1] + bias4[ns]) << 16);
          pk.y = (unsigned)f2bf(acc[ms][ns][2] + bias4[ns]) |
                 ((unsigned)f2bf(acc[ms][ns][3] + bias4[ns]) << 16);
          *(uint2*)(out + (((size_t)batch * H_ + hh) * DK + d) * LP + lrow0) = pk;
        }
      }
    }
  } else {
#pragma unroll
    for (int ms = 0; ms < 4; ++ms) {
#pragma unroll
      for (int r = 0; r < 4; ++r) {
        const int m = tm * 128 + wr * 64 + ms * 16 + lg * 4 + r;
        if (m < 4000) {
          const unsigned batch = (unsigned)m / 500u;
          const int lrow = m - (int)batch * 500;
#pragma unroll
          for (int ns = 0; ns < 4; ++ns) {
            const int n = nbase + ns * 16;
            const int hh = n >> 6, d = n & 63;
            out[(((size_t)batch * H_ + hh) * LP + lrow) * DK + d] =
                f2bf(acc[ms][ns][r] + bias4[ns]);
          }
        }
      }
    }
  }
}

// ---------- flash attention: QBLK=128, 8 waves, staged K/V, sigma-permuted QK^T,
//            P entirely in registers ----------
__global__ __launch_bounds__(512, 2) void attn_kernel(
    const unsigned short* __restrict__ q, const unsigned short* __restrict__ k,
    const unsigned short* __restrict__ vt, const float* __restrict__ rel,
    float* __restrict__ out) {
  const int id = blockIdx.x;           // XCD = id%8 = bh%8 -> per-XCD K/V L2 residency
  const int bh = id & 127, qc = id >> 7;   // qc 0..3, 128 q-rows each
  const int b = bh >> 4, h = bh & 15;
  const int tid = threadIdx.x;
  const int lane = tid & 63, wid = tid >> 6;    // 8 waves
  const int lg = lane >> 4, lr = lane & 15;

  __shared__ unsigned short kt[2][2][64][32];   // [buf][dhalf][key][d&31]
  __shared__ unsigned short vtt[2][2][64][32];  // [buf][keyhalf][d][key&31]
  __shared__ float relb[640];

  const float LOG2E = 1.44269504f;
  const float SC = 0.125f * LOG2E;
  const int rbase = qc * 128 - 12;
  for (int i = tid; i < 639; i += 512) {
    int idx = rbase + i;
    idx = idx < 0 ? 0 : (idx > 998 ? 998 : idx);
    relb[i] = rel[h * 999 + idx] * LOG2E;
  }

  const int qrow = qc * 128 + wid * 16 + lr;
  const unsigned short* qp = q + ((size_t)bh * LP + qrow) * DK + lg * 8;
  const bf16x8 qf0 = *(const bf16x8*)qp;
  const bf16x8 qf1 = *(const bf16x8*)(qp + 32);

  const int kj = tid >> 3, dcs = (tid & 7) * 8;
  const unsigned short* kgp = k + ((size_t)bh * LP + kj) * DK + dcs;
  unsigned short* kls = &kt[0][dcs >> 5][kj][dcs & 31];
  const int vd = tid >> 3, vkg = (tid & 7) * 8;
  const unsigned short* vgp = vt + ((size_t)bh * DK + vd) * LP + vkg;
  unsigned short* vls = &vtt[0][vkg >> 5][vd][vkg & 31];

  const int sig0 = 8 * (lr >> 2) + (lr & 3);   // sigma base
  const int qin = wid * 16 + lr;               // 0..127

  f32x4 o[4];
#pragma unroll
  for (int d = 0; d < 4; ++d) o[d] = (f32x4){0.f, 0.f, 0.f, 0.f};
  float mrun = -1e30f, lrun = 0.f;

  uint4 ka0 = *(const uint4*)(kgp);
  uint4 va0 = *(const uint4*)(vgp);

  for (int t = 0; t < NT; ++t) {
    const int buf = t & 1;
    *(uint4*)(kls + buf * 4096) = ka0;
    *(uint4*)(vls + buf * 4096) = va0;
    __syncthreads();

    if (t < NT - 1) {
      ka0 = *(const uint4*)(kgp + (size_t)(t + 1) * 64 * DK);
      va0 = *(const uint4*)(vgp + (t + 1) * 64);
    }

    f32x4 s[2][2];
#pragma unroll
    for (int kc = 0; kc < 2; ++kc)
#pragma unroll
      for (int hf = 0; hf < 2; ++hf) {
        const int sg = kc * 32 + hf * 4 + sig0;
        const bf16x8 a0 = *(const bf16x8*)&kt[buf][0][sg][lg * 8];
        const bf16x8 a1 = *(const bf16x8*)&kt[buf][1][sg][lg * 8];
        f32x4 ss = (f32x4){0.f, 0.f, 0.f, 0.f};
        ss = __builtin_amdgcn_mfma_f32_16x16x32_bf16(a0, qf0, ss, 0, 0, 0);
        ss = __builtin_amdgcn_mfma_f32_16x16x32_bf16(a1, qf1, ss, 0, 0, 0);
        s[kc][hf] = ss;
      }

    float sc[2][2][4];
#pragma unroll
    for (int kc = 0; kc < 2; ++kc)
#pragma unroll
      for (int hf = 0; hf < 2; ++hf) {
        const int bidx = qin - (t * 64 + kc * 32 + 8 * lg + 4 * hf) + 511;
#pragma unroll
        for (int r = 0; r < 4; ++r)
          sc[kc][hf][r] = s[kc][hf][r] * SC + relb[bidx - r];
      }
    if (t == NT - 1) {
#pragma unroll
      for (int hf = 0; hf < 2; ++hf)
#pragma unroll
        for (int r = 0; r < 4; ++r)
          if (8 * lg + 4 * hf + r >= 20) sc[1][hf][r] = -1e30f;
    }

    float m0 = fmaxf(fmaxf(sc[0][0][0], sc[0][0][1]), fmaxf(sc[0][0][2], sc[0][0][3]));
    float m1 = fmaxf(fmaxf(sc[0][1][0], sc[0][1][1]), fmaxf(sc[0][1][2], sc[0][1][3]));
    float m2 = fmaxf(fmaxf(sc[1][0][0], sc[1][0][1]), fmaxf(sc[1][0][2], sc[1][0][3]));
    float m3 = fmaxf(fmaxf(sc[1][1][0], sc[1][1][1]), fmaxf(sc[1][1][2], sc[1][1][3]));
    const float mloc = fmaxf(fmaxf(m0, m1), fmaxf(m2, m3));
    if (!__all(mloc - mrun <= 11.5f)) {
      float mx = fmaxf(mloc, mrun);
      mx = fmaxf(mx, __shfl_xor(mx, 16));
      mx = fmaxf(mx, __shfl_xor(mx, 32));
      const float alpha = exp2f(mrun - mx);
      mrun = mx;
      lrun *= alpha;
#pragma unroll
      for (int d = 0; d < 4; ++d) {
        o[d][0] *= alpha; o[d][1] *= alpha; o[d][2] *= alpha; o[d][3] *= alpha;
      }
    }

    float rs = 0.f;
    unsigned pw[2][4];
#pragma unroll
    for (int kc = 0; kc < 2; ++kc)
#pragma unroll
      for (int hf = 0; hf < 2; ++hf) {
        float p0 = exp2f(sc[kc][hf][0] - mrun);
        float p1 = exp2f(sc[kc][hf][1] - mrun);
        float p2 = exp2f(sc[kc][hf][2] - mrun);
        float p3 = exp2f(sc[kc][hf][3] - mrun);
        rs += (p0 + p1) + (p2 + p3);
        pw[kc][hf * 2 + 0] = cvtpk(p0, p1);
        pw[kc][hf * 2 + 1] = cvtpk(p2, p3);
      }
    rs += __shfl_xor(rs, 16);
    rs += __shfl_xor(rs, 32);
    lrun += rs;

#pragma unroll
    for (int kc = 0; kc < 2; ++kc) {
      union { uint4v u; bf16x8 v; } cv;
      cv.u = (uint4v){pw[kc][0], pw[kc][1], pw[kc][2], pw[kc][3]};
      const bf16x8 pf = cv.v;
#pragma unroll
      for (int db = 0; db < 4; ++db) {
        const bf16x8 vf = *(const bf16x8*)&vtt[buf][kc][db * 16 + lr][lg * 8];
        o[db] = __builtin_amdgcn_mfma_f32_16x16x32_bf16(vf, pf, o[db], 0, 0, 0);
      }
    }
  }

  if (qrow < L_) {
    const float inv = 1.0f / lrun;
    float* op = out + ((size_t)b * L_ + qrow) * DM + h * DK + lg * 4;
#pragma unroll
    for (int db = 0; db < 4; ++db) {
      float4 v;
      v.x = o[db][0] * inv; v.y = o[db][1] * inv;
      v.z = o[db][2] * inv; v.w = o[db][3] * inv;
      *(float4*)(op + db * 16) = v;
    }
  }
}

extern "C" void kernel_launch(void* const* d_in, const int* in_sizes, int n_in,
                              void* d_out, int out_size, void* d_ws, size_t ws_size,
                              hipStream_t stream) {
  const float* iq  = (const float*)d_in[0];
  const float* ik  = (const float*)d_in[1];
  const float* iv  = (const float*)d_in[2];
  const float* wq  = (const float*)d_in[3];
  const float* bq  = (const float*)d_in[4];
  const float* wk  = (const float*)d_in[5];
  const float* bk  = (const float*)d_in[6];
  const float* wv  = (const float*)d_in[7];
  const float* bv  = (const float*)d_in[8];
  const float* rel = (const float*)d_in[9];
  float* out = (float*)d_out;

  char* w = (char*)d_ws;
  unsigned short* X   = (unsigned short*)(w);                 // [3][4096][1024] bf16
  unsigned short* Wt  = (unsigned short*)(w + 25165824);      // [3][1024][1024] bf16 (n,k)
  unsigned short* qb  = (unsigned short*)(w + 31457280);      // [128][512][64] bf16
  unsigned short* kb  = (unsigned short*)(w + 39845888);
  unsigned short* vtb = (unsigned short*)(w + 48234496);      // [128][64][512] bf16 (V^T)

  conv_kernel<<<dim3(2336, 3), 256, 0, stream>>>(iq, ik, iv, wq, wk, wv, X, Wt, vtb);
  gemm_qkv_kernel<<<dim3(256, 3), 256, 0, stream>>>(X, Wt, bq, bk, bv, qb, kb, vtb);
  attn_kernel<<<512, 512, 0, stream>>>(qb, kb, vtb, rel, out);
}

// Round 13
// 83.200 us; speedup vs baseline: 1.1446x; 1.0132x over previous
//
#include <hip/hip_runtime.h>

typedef short bf16x8 __attribute__((ext_vector_type(8)));
typedef float f32x4 __attribute__((ext_vector_type(4)));
typedef unsigned uint4v __attribute__((ext_vector_type(4)));

#define B_    8
#define L_    500
#define LP    512
#define H_    16
#define DK    64
#define DM    1024
#define MP    4096
#define NT    8      // attn: 512 / 64 keys per tile

static __device__ __forceinline__ unsigned short f2bf(float x) {
  unsigned u = __float_as_uint(x);
  u += 0x7fffu + ((u >> 16) & 1u);   // RNE
  return (unsigned short)(u >> 16);
}

static __device__ __forceinline__ unsigned cvtpk(float lo, float hi) {
  unsigned r;
  asm("v_cvt_pk_bf16_f32 %0, %1, %2" : "=v"(r) : "v"(lo), "v"(hi));
  return r;
}

static __device__ __forceinline__ void gload16(const void* g, void* l) {
  __builtin_amdgcn_global_load_lds(
      (const __attribute__((address_space(1))) void*)g,
      (__attribute__((address_space(3))) void*)l, 16, 0, 0);
}

static __device__ __forceinline__ f32x4 MF(bf16x8 a, bf16x8 b, f32x4 c) {
  return __builtin_amdgcn_mfma_f32_16x16x32_bf16(a, b, c, 0, 0, 0);
}

// ---------- merged prep: conv_x (bx<2048) + conv_w (2048<=bx<2304) + vt tail zero ----------
__global__ __launch_bounds__(256) void conv_kernel(
    const float* __restrict__ iq, const float* __restrict__ ik,
    const float* __restrict__ iv,
    const float* __restrict__ wq, const float* __restrict__ wk,
    const float* __restrict__ wv,
    unsigned short* __restrict__ X, unsigned short* __restrict__ Wt,
    unsigned short* __restrict__ vt) {
  const int z = blockIdx.y;
  const int bx = blockIdx.x;
  const int tid = threadIdx.x;
  if (bx < 2048) {
    const float* src = (z == 0) ? iq : (z == 1) ? ik : iv;
    const size_t off = ((size_t)bx * 256 + tid) * 8;
    const int m = (int)(off >> 10);
    unsigned short o[8];
    if (m < 4000) {
      const float4 a = *(const float4*)(src + off);
      const float4 b = *(const float4*)(src + off + 4);
      o[0]=f2bf(a.x); o[1]=f2bf(a.y); o[2]=f2bf(a.z); o[3]=f2bf(a.w);
      o[4]=f2bf(b.x); o[5]=f2bf(b.y); o[6]=f2bf(b.z); o[7]=f2bf(b.w);
    } else {
#pragma unroll
      for (int i = 0; i < 8; ++i) o[i] = 0;
    }
    uint4 pk;
    pk.x = (unsigned)o[0] | ((unsigned)o[1] << 16);
    pk.y = (unsigned)o[2] | ((unsigned)o[3] << 16);
    pk.z = (unsigned)o[4] | ((unsigned)o[5] << 16);
    pk.w = (unsigned)o[6] | ((unsigned)o[7] << 16);
    *(uint4*)(X + (size_t)z * MP * DM + off) = pk;
    return;
  }
  if (bx >= 2304) {
    // zero V^T rows l in [496,512) for all (bh, d); gemm later overwrites 496..499
    if (z == 0) {
      const int idx = (bx - 2304) * 256 + tid;      // 0..8191 = bh*64 + d
      unsigned short* p = vt + (size_t)idx * LP + 496;
      const uint4 zz = {0u, 0u, 0u, 0u};
      *(uint4*)(p)     = zz;
      *(uint4*)(p + 8) = zz;
    }
    return;
  }
  const int bw = bx - 2048;
  const float* W = (z == 0) ? wq : (z == 1) ? wk : wv;
  const int k0 = (bw >> 4) * 64;
  const int n0 = (bw & 15) * 64;
  __shared__ float t[64][65];
  const int row = tid >> 2;
  const int cb  = (tid & 3) * 16;
#pragma unroll
  for (int s = 0; s < 4; ++s) {
    const float4 v = *(const float4*)(W + (size_t)(k0 + row) * DM + n0 + cb + s * 4);
    t[row][cb + s * 4 + 0] = v.x; t[row][cb + s * 4 + 1] = v.y;
    t[row][cb + s * 4 + 2] = v.z; t[row][cb + s * 4 + 3] = v.w;
  }
  __syncthreads();
  const int nr = tid >> 2;
  const int kb = (tid & 3) * 16;
#pragma unroll
  for (int s = 0; s < 2; ++s) {
    unsigned short o[8];
#pragma unroll
    for (int e = 0; e < 8; ++e) o[e] = f2bf(t[kb + s * 8 + e][nr]);
    uint4 pk;
    pk.x = (unsigned)o[0] | ((unsigned)o[1] << 16);
    pk.y = (unsigned)o[2] | ((unsigned)o[3] << 16);
    pk.z = (unsigned)o[4] | ((unsigned)o[5] << 16);
    pk.w = (unsigned)o[6] | ((unsigned)o[7] << 16);
    *(uint4*)(Wt + (size_t)z * DM * DM + (size_t)(n0 + nr) * DM + k0 + kb + s * 8) = pk;
  }
}

// ---------- fused QKV projection GEMM (m97 structure + 3-buffer counted-vmcnt ring) ----------
// z==0/1 write q/k in [b][h][l(512)][64]; z==2 writes V^T [b*16+h][d][l(512)] via
// per-wave LDS transpose in TWO 32-d halves (fits the 8KB dead buffers).
__global__ __launch_bounds__(256) void gemm_qkv_kernel(
    const unsigned short* __restrict__ X, const unsigned short* __restrict__ Wt,
    const float* __restrict__ bq, const float* __restrict__ bk,
    const float* __restrict__ bv,
    unsigned short* __restrict__ qo, unsigned short* __restrict__ ko,
    unsigned short* __restrict__ vo) {
  const int z = blockIdx.y;
  const unsigned short* A  = X  + (size_t)z * MP * DM;
  const unsigned short* Bw = Wt + (size_t)z * DM * DM;
  const float* bias = (z == 0) ? bq : (z == 1) ? bk : bv;
  unsigned short* out = (z == 0) ? qo : (z == 1) ? ko : vo;

  const int bid = blockIdx.x;
  const int xg = bid & 7, y = bid >> 3;
  const int tm = xg + 8 * (y >> 3);           // 0..31
  const int tn = y & 7;                       // 0..7
  const int tid = threadIdx.x;
  const int lane = tid & 63, wid = tid >> 6;
  const int wr = wid >> 1, wc = wid & 1;
  const int lg = lane >> 4, lr = lane & 15;

  __shared__ __attribute__((aligned(16))) unsigned short sA[3][128 * 32];
  __shared__ __attribute__((aligned(16))) unsigned short sB[3][128 * 32];

  const int c0 = tid, c1 = tid + 256;
  const int ar0 = c0 >> 2, ak0 = (c0 & 3) * 8;
  const int ar1 = c1 >> 2, ak1 = (c1 & 3) * 8;
  const unsigned short* Ab = A  + (size_t)tm * 128 * DM;
  const unsigned short* Bb = Bw + (size_t)tn * 128 * DM;

  auto STAGE = [&](int t) {
    const int buf = t % 3;
    const int kn = t * 32;
    gload16(Ab + (size_t)ar0 * DM + kn + ak0, &sA[buf][c0 * 8]);
    gload16(Ab + (size_t)ar1 * DM + kn + ak1, &sA[buf][c1 * 8]);
    gload16(Bb + (size_t)ar0 * DM + kn + ak0, &sB[buf][c0 * 8]);
    gload16(Bb + (size_t)ar1 * DM + kn + ak1, &sB[buf][c1 * 8]);
  };

  f32x4 acc[4][4];
#pragma unroll
  for (int i = 0; i < 4; ++i)
#pragma unroll
    for (int j = 0; j < 4; ++j) acc[i][j] = (f32x4){0.f, 0.f, 0.f, 0.f};

  // prologue: tiles 0,1 in flight; wait tile0 (leave tile1's 4 loads in flight)
  STAGE(0); STAGE(1);
  asm volatile("s_waitcnt vmcnt(4)" ::: "memory");
  __builtin_amdgcn_s_barrier();
  __builtin_amdgcn_sched_barrier(0);

  for (int t = 0; t < 32; ++t) {
    if (t < 30) STAGE(t + 2);               // issue into buf (t+2)%3 (last read at t-1)
    const int cb = t % 3;
    bf16x8 af[4], bfr[4];
#pragma unroll
    for (int s = 0; s < 4; ++s) {
      af[s]  = *(const bf16x8*)&sA[cb][(wr * 64 + s * 16 + lr) * 32 + lg * 8];
      bfr[s] = *(const bf16x8*)&sB[cb][(wc * 64 + s * 16 + lr) * 32 + lg * 8];
    }
#pragma unroll
    for (int i = 0; i < 4; ++i)
#pragma unroll
      for (int j = 0; j < 4; ++j)
        acc[i][j] = MF(af[i], bfr[j], acc[i][j]);
    if (t < 31) {
      if (t < 30) asm volatile("s_waitcnt vmcnt(4)" ::: "memory");  // t+1 landed, t+2 in flight
      else        asm volatile("s_waitcnt vmcnt(0)" ::: "memory");  // tail: t=30 waits tile31
      __builtin_amdgcn_s_barrier();
      __builtin_amdgcn_sched_barrier(0);
    }
  }

  const int nbase = tn * 128 + wc * 64 + lr;
  float bias4[4];
#pragma unroll
  for (int ns = 0; ns < 4; ++ns) bias4[ns] = bias[nbase + ns * 16];

  if (z == 2) {
    // per-wave transpose buffer (8KB, dead after t=30 barrier; t=31 uses only buf 1).
    // Two passes of 32 d-rows each: [32][72] = 2304 shorts << 4096 (fits; R12 overflowed).
    unsigned short* T = (wid == 0) ? &sA[0][0] : (wid == 1) ? &sA[2][0]
                      : (wid == 2) ? &sB[0][0] : &sB[2][0];
    const int hh = tn * 2 + wc;
    const int m0w = tm * 128 + wr * 64;
    const int li = lane & 15;                 // this lane's l-chunk of 4
    const int m = m0w + li * 4;
    const unsigned batch = (unsigned)m / 500u;
    const int lrow = m - (int)batch * 500;    // chunk never straddles 500 (500 % 4 == 0)
    unsigned short* ob = out + (((size_t)batch * H_ + hh) * DK) * LP + lrow;
    const bool ok = (m < 4000);
#pragma unroll
    for (int half = 0; half < 2; ++half) {
      // write phase: d-local = nsl*16 + lr (0..31), l-local = ms*16 + lg*4 (+0..3)
#pragma unroll
      for (int ms = 0; ms < 4; ++ms)
#pragma unroll
        for (int nsl = 0; nsl < 2; ++nsl) {
          const int ns = half * 2 + nsl;
          uint2 pk;
          pk.x = (unsigned)f2bf(acc[ms][ns][0] + bias4[ns]) |
                 ((unsigned)f2bf(acc[ms][ns][1] + bias4[ns]) << 16);
          pk.y = (unsigned)f2bf(acc[ms][ns][2] + bias4[ns]) |
                 ((unsigned)f2bf(acc[ms][ns][3] + bias4[ns]) << 16);
          *(uint2*)&T[(nsl * 16 + lr) * 72 + ms * 16 + lg * 4] = pk;
        }
      asm volatile("s_waitcnt lgkmcnt(0)" ::: "memory");   // writes visible in-wave
      __builtin_amdgcn_sched_barrier(0);
      // read+store phase: lane covers d-local = it*4 + lg, its own l-chunk li*4
      if (ok) {
#pragma unroll
        for (int it = 0; it < 8; ++it) {
          const int dl = it * 4 + lg;          // 0..31
          const uint2 v = *(const uint2*)&T[dl * 72 + li * 4];
          *(uint2*)(ob + (size_t)(half * 32 + dl) * LP) = v;
        }
      }
      asm volatile("s_waitcnt lgkmcnt(0)" ::: "memory");   // reads done before reuse
      __builtin_amdgcn_sched_barrier(0);
    }
  } else {
#pragma unroll
    for (int ms = 0; ms < 4; ++ms) {
#pragma unroll
      for (int r = 0; r < 4; ++r) {
        const int m = tm * 128 + wr * 64 + ms * 16 + lg * 4 + r;
        if (m < 4000) {
          const unsigned batch = (unsigned)m / 500u;
          const int lrow = m - (int)batch * 500;
#pragma unroll
          for (int ns = 0; ns < 4; ++ns) {
            const int n = nbase + ns * 16;
            const int hh = n >> 6, d = n & 63;
            out[(((size_t)batch * H_ + hh) * LP + lrow) * DK + d] =
                f2bf(acc[ms][ns][r] + bias4[ns]);
          }
        }
      }
    }
  }
}

// ---------- flash attention: QBLK=128, 8 waves, staged K/V, sigma-permuted QK^T,
//            P entirely in registers ----------
__global__ __launch_bounds__(512, 2) void attn_kernel(
    const unsigned short* __restrict__ q, const unsigned short* __restrict__ k,
    const unsigned short* __restrict__ vt, const float* __restrict__ rel,
    float* __restrict__ out) {
  const int id = blockIdx.x;           // XCD = id%8 = bh%8 -> per-XCD K/V L2 residency
  const int bh = id & 127, qc = id >> 7;   // qc 0..3, 128 q-rows each
  const int b = bh >> 4, h = bh & 15;
  const int tid = threadIdx.x;
  const int lane = tid & 63, wid = tid >> 6;    // 8 waves
  const int lg = lane >> 4, lr = lane & 15;

  __shared__ unsigned short kt[2][2][64][32];   // [buf][dhalf][key][d&31]
  __shared__ unsigned short vtt[2][2][64][32];  // [buf][keyhalf][d][key&31]
  __shared__ float relb[640];

  const float LOG2E = 1.44269504f;
  const float SC = 0.125f * LOG2E;
  const int rbase = qc * 128 - 12;
  for (int i = tid; i < 639; i += 512) {
    int idx = rbase + i;
    idx = idx < 0 ? 0 : (idx > 998 ? 998 : idx);
    relb[i] = rel[h * 999 + idx] * LOG2E;
  }

  const int qrow = qc * 128 + wid * 16 + lr;
  const unsigned short* qp = q + ((size_t)bh * LP + qrow) * DK + lg * 8;
  const bf16x8 qf0 = *(const bf16x8*)qp;
  const bf16x8 qf1 = *(const bf16x8*)(qp + 32);

  const int kj = tid >> 3, dcs = (tid & 7) * 8;
  const unsigned short* kgp = k + ((size_t)bh * LP + kj) * DK + dcs;
  unsigned short* kls = &kt[0][dcs >> 5][kj][dcs & 31];
  const int vd = tid >> 3, vkg = (tid & 7) * 8;
  const unsigned short* vgp = vt + ((size_t)bh * DK + vd) * LP + vkg;
  unsigned short* vls = &vtt[0][vkg >> 5][vd][vkg & 31];

  const int sig0 = 8 * (lr >> 2) + (lr & 3);   // sigma base
  const int qin = wid * 16 + lr;               // 0..127

  f32x4 o[4];
#pragma unroll
  for (int d = 0; d < 4; ++d) o[d] = (f32x4){0.f, 0.f, 0.f, 0.f};
  float mrun = -1e30f, lrun = 0.f;

  uint4 ka0 = *(const uint4*)(kgp);
  uint4 va0 = *(const uint4*)(vgp);

  for (int t = 0; t < NT; ++t) {
    const int buf = t & 1;
    *(uint4*)(kls + buf * 4096) = ka0;
    *(uint4*)(vls + buf * 4096) = va0;
    __syncthreads();

    if (t < NT - 1) {
      ka0 = *(const uint4*)(kgp + (size_t)(t + 1) * 64 * DK);
      va0 = *(const uint4*)(vgp + (t + 1) * 64);
    }

    f32x4 s[2][2];
#pragma unroll
    for (int kc = 0; kc < 2; ++kc)
#pragma unroll
      for (int hf = 0; hf < 2; ++hf) {
        const int sg = kc * 32 + hf * 4 + sig0;
        const bf16x8 a0 = *(const bf16x8*)&kt[buf][0][sg][lg * 8];
        const bf16x8 a1 = *(const bf16x8*)&kt[buf][1][sg][lg * 8];
        f32x4 ss = (f32x4){0.f, 0.f, 0.f, 0.f};
        ss = __builtin_amdgcn_mfma_f32_16x16x32_bf16(a0, qf0, ss, 0, 0, 0);
        ss = __builtin_amdgcn_mfma_f32_16x16x32_bf16(a1, qf1, ss, 0, 0, 0);
        s[kc][hf] = ss;
      }

    float sc[2][2][4];
#pragma unroll
    for (int kc = 0; kc < 2; ++kc)
#pragma unroll
      for (int hf = 0; hf < 2; ++hf) {
        const int bidx = qin - (t * 64 + kc * 32 + 8 * lg + 4 * hf) + 511;
#pragma unroll
        for (int r = 0; r < 4; ++r)
          sc[kc][hf][r] = s[kc][hf][r] * SC + relb[bidx - r];
      }
    if (t == NT - 1) {
#pragma unroll
      for (int hf = 0; hf < 2; ++hf)
#pragma unroll
        for (int r = 0; r < 4; ++r)
          if (8 * lg + 4 * hf + r >= 20) sc[1][hf][r] = -1e30f;
    }

    float m0 = fmaxf(fmaxf(sc[0][0][0], sc[0][0][1]), fmaxf(sc[0][0][2], sc[0][0][3]));
    float m1 = fmaxf(fmaxf(sc[0][1][0], sc[0][1][1]), fmaxf(sc[0][1][2], sc[0][1][3]));
    float m2 = fmaxf(fmaxf(sc[1][0][0], sc[1][0][1]), fmaxf(sc[1][0][2], sc[1][0][3]));
    float m3 = fmaxf(fmaxf(sc[1][1][0], sc[1][1][1]), fmaxf(sc[1][1][2], sc[1][1][3]));
    const float mloc = fmaxf(fmaxf(m0, m1), fmaxf(m2, m3));
    if (!__all(mloc - mrun <= 11.5f)) {
      float mx = fmaxf(mloc, mrun);
      mx = fmaxf(mx, __shfl_xor(mx, 16));
      mx = fmaxf(mx, __shfl_xor(mx, 32));
      const float alpha = exp2f(mrun - mx);
      mrun = mx;
      lrun *= alpha;
#pragma unroll
      for (int d = 0; d < 4; ++d) {
        o[d][0] *= alpha; o[d][1] *= alpha; o[d][2] *= alpha; o[d][3] *= alpha;
      }
    }

    float rs = 0.f;
    unsigned pw[2][4];
#pragma unroll
    for (int kc = 0; kc < 2; ++kc)
#pragma unroll
      for (int hf = 0; hf < 2; ++hf) {
        float p0 = exp2f(sc[kc][hf][0] - mrun);
        float p1 = exp2f(sc[kc][hf][1] - mrun);
        float p2 = exp2f(sc[kc][hf][2] - mrun);
        float p3 = exp2f(sc[kc][hf][3] - mrun);
        rs += (p0 + p1) + (p2 + p3);
        pw[kc][hf * 2 + 0] = cvtpk(p0, p1);
        pw[kc][hf * 2 + 1] = cvtpk(p2, p3);
      }
    rs += __shfl_xor(rs, 16);
    rs += __shfl_xor(rs, 32);
    lrun += rs;

#pragma unroll
    for (int kc = 0; kc < 2; ++kc) {
      union { uint4v u; bf16x8 v; } cv;
      cv.u = (uint4v){pw[kc][0], pw[kc][1], pw[kc][2], pw[kc][3]};
      const bf16x8 pf = cv.v;
#pragma unroll
      for (int db = 0; db < 4; ++db) {
        const bf16x8 vf = *(const bf16x8*)&vtt[buf][kc][db * 16 + lr][lg * 8];
        o[db] = __builtin_amdgcn_mfma_f32_16x16x32_bf16(vf, pf, o[db], 0, 0, 0);
      }
    }
  }

  if (qrow < L_) {
    const float inv = 1.0f / lrun;
    float* op = out + ((size_t)b * L_ + qrow) * DM + h * DK + lg * 4;
#pragma unroll
    for (int db = 0; db < 4; ++db) {
      float4 v;
      v.x = o[db][0] * inv; v.y = o[db][1] * inv;
      v.z = o[db][2] * inv; v.w = o[db][3] * inv;
      *(float4*)(op + db * 16) = v;
    }
  }
}

extern "C" void kernel_launch(void* const* d_in, const int* in_sizes, int n_in,
                              void* d_out, int out_size, void* d_ws, size_t ws_size,
                              hipStream_t stream) {
  const float* iq  = (const float*)d_in[0];
  const float* ik  = (const float*)d_in[1];
  const float* iv  = (const float*)d_in[2];
  const float* wq  = (const float*)d_in[3];
  const float* bq  = (const float*)d_in[4];
  const float* wk  = (const float*)d_in[5];
  const float* bk  = (const float*)d_in[6];
  const float* wv  = (const float*)d_in[7];
  const float* bv  = (const float*)d_in[8];
  const float* rel = (const float*)d_in[9];
  float* out = (float*)d_out;

  char* w = (char*)d_ws;
  unsigned short* X   = (unsigned short*)(w);                 // [3][4096][1024] bf16
  unsigned short* Wt  = (unsigned short*)(w + 25165824);      // [3][1024][1024] bf16 (n,k)
  unsigned short* qb  = (unsigned short*)(w + 31457280);      // [128][512][64] bf16
  unsigned short* kb  = (unsigned short*)(w + 39845888);
  unsigned short* vtb = (unsigned short*)(w + 48234496);      // [128][64][512] bf16 (V^T)

  conv_kernel<<<dim3(2336, 3), 256, 0, stream>>>(iq, ik, iv, wq, wk, wv, X, Wt, vtb);
  gemm_qkv_kernel<<<dim3(256, 3), 256, 0, stream>>>(X, Wt, bq, bk, bv, qb, kb, vtb);
  attn_kernel<<<512, 512, 0, stream>>>(qb, kb, vtb, rel, out);
}